// Round 15
// baseline (316.812 us; speedup 1.0000x reference)
//
#include <hip/hip_runtime.h>
#include <hip/hip_fp16.h>

#define CCH 64      // channels
#define HCH 32      // channels per plane
#define RPB 32      // rows per bucket
#define PCH 8192    // edges per partition block
#define NBMAX 1568  // >= NB = ceil(50000/32) = 1563
#define GR 64       // rows per gemm block
#define SG 8        // buckets per sort block

typedef int int4a __attribute__((ext_vector_type(4), aligned(4)));

// ---- pass A: per-block bucket histogram -> H[c][blk][b] ----
__global__ void __launch_bounds__(256) k_hist(const int* __restrict__ e0,
        const int* __restrict__ e1, const int* __restrict__ e2,
        int* __restrict__ H, int E, int NB, int NBLK) {
    int c = blockIdx.y;
    const int* dd = ((c == 0) ? e0 : (c == 1) ? e1 : e2) + E;
    int base = blockIdx.x * PCH;
    int nE = E - base; if (nE > PCH) nE = PCH;
    __shared__ int hist[NBMAX];
    int t = threadIdx.x;
    for (int i = t; i < NB; i += 256) hist[i] = 0;
    __syncthreads();
    for (int k = t * 4; k < nE; k += 1024) {
        if (k + 3 < nE) {
            int4a d = *(const int4a*)(dd + base + k);
            atomicAdd(&hist[d.x >> 5], 1); atomicAdd(&hist[d.y >> 5], 1);
            atomicAdd(&hist[d.z >> 5], 1); atomicAdd(&hist[d.w >> 5], 1);
        } else {
            for (int j = k; j < nE; ++j) atomicAdd(&hist[dd[base + j] >> 5], 1);
        }
    }
    __syncthreads();
    int* Hrow = H + ((size_t)c * NBLK + blockIdx.x) * NB;
    for (int i = t; i < NB; i += 256) Hrow[i] = hist[i];
}

// ---- column-sum H over blocks + exclusive scan -> bstart (no cnt/zero) ----
__global__ void __launch_bounds__(1024) k_bscan(const int* __restrict__ H,
        int* __restrict__ bstart, int NB, int NBLK, int E) {
    int c = blockIdx.x, t = threadIdx.x;
    __shared__ int sm[1024];
    int i0 = 2 * t, i1 = 2 * t + 1;
    int v0 = 0, v1 = 0;
    const int* Hc = H + (size_t)c * NBLK * NB;
    if (i0 < NB) for (int b = 0; b < NBLK; ++b) v0 += Hc[(size_t)b * NB + i0];
    if (i1 < NB) for (int b = 0; b < NBLK; ++b) v1 += Hc[(size_t)b * NB + i1];
    sm[t] = v0 + v1;
    __syncthreads();
    #pragma unroll
    for (int off = 1; off < 1024; off <<= 1) {
        int u = (t >= off) ? sm[t - off] : 0;
        __syncthreads();
        sm[t] += u;
        __syncthreads();
    }
    int ex = sm[t] - (v0 + v1);
    if (i0 < NB) bstart[c * (NB + 1) + i0] = ex;
    if (i1 < NB) bstart[c * (NB + 1) + i1] = ex + v0;
    if (t == 0) bstart[c * (NB + 1) + NB] = E;
}

// ---- pass B: per-bucket scan over blocks: H <- bstart + prefix ----
__global__ void __launch_bounds__(256) k_colscan(int* __restrict__ H,
        const int* __restrict__ bstart, int NB, int NBLK) {
    int c = blockIdx.y;
    int b = blockIdx.x * 4 + (threadIdx.x >> 6);
    if (b >= NB) return;
    int l = threadIdx.x & 63;
    int* Hc = H + (size_t)c * NBLK * NB;
    int run = bstart[c * (NB + 1) + b];
    for (int c0 = 0; c0 < NBLK; c0 += 64) {
        int blk = c0 + l;
        int v = (blk < NBLK) ? Hc[(size_t)blk * NB + b] : 0;
        int s = v;
        #pragma unroll
        for (int off = 1; off < 64; off <<= 1) {
            int u = __shfl_up(s, off, 64);
            if (l >= off) s += u;
        }
        if (blk < NBLK) Hc[(size_t)blk * NB + b] = run + s - v;
        run += __shfl(s, 63, 64);
    }
}

// ---- pass C: LDS-STAGED partition (bucket-ordered staging, linear copy-out) ----
__global__ void __launch_bounds__(256) k_part2(const int* __restrict__ e0,
        const int* __restrict__ e1, const int* __restrict__ e2,
        const int* __restrict__ H, unsigned* __restrict__ bdata,
        int E, int NB, int NBLK) {
    int c = blockIdx.y;
    const int* ed = (c == 0) ? e0 : (c == 1) ? e1 : e2;
    int base = blockIdx.x * PCH;
    int nE = E - base; if (nE > PCH) nE = PCH;
    __shared__ unsigned staged[PCH];    // 32 KB
    __shared__ int hist[NBMAX];
    __shared__ int off[NBMAX];
    __shared__ int sm[256];
    int t = threadIdx.x;
    for (int i = t; i < NB; i += 256) hist[i] = 0;
    const int* Hrow = H + ((size_t)c * NBLK + blockIdx.x) * NB;
    for (int i = t; i < NB; i += 256) off[i] = Hrow[i];
    __syncthreads();
    for (int k = t * 4; k < nE; k += 1024) {
        if (k + 3 < nE) {
            int4a d = *(const int4a*)(ed + E + base + k);
            atomicAdd(&hist[d.x >> 5], 1); atomicAdd(&hist[d.y >> 5], 1);
            atomicAdd(&hist[d.z >> 5], 1); atomicAdd(&hist[d.w >> 5], 1);
        } else {
            for (int j = k; j < nE; ++j) atomicAdd(&hist[ed[E + base + j] >> 5], 1);
        }
    }
    __syncthreads();
    int C = (NB + 255) >> 8;
    int lo = t * C, hi = lo + C; if (hi > NB) hi = NB; if (lo > NB) lo = NB;
    int s = 0;
    for (int i = lo; i < hi; ++i) s += hist[i];
    sm[t] = s;
    __syncthreads();
    #pragma unroll
    for (int o = 1; o < 256; o <<= 1) {
        int u = (t >= o) ? sm[t - o] : 0;
        __syncthreads();
        sm[t] += u;
        __syncthreads();
    }
    int run = (t == 0) ? 0 : sm[t - 1];
    for (int i = lo; i < hi; ++i) {
        int h = hist[i];
        off[i] -= run;
        hist[i] = run;
        run += h;
    }
    __syncthreads();
    for (int k = t * 4; k < nE; k += 1024) {
        if (k + 3 < nE) {
            int4a s4 = *(const int4a*)(ed + base + k);
            int4a d4 = *(const int4a*)(ed + E + base + k);
            int sl;
            sl = atomicAdd(&hist[d4.x >> 5], 1); staged[sl] = (unsigned)s4.x | ((unsigned)d4.x << 16);
            sl = atomicAdd(&hist[d4.y >> 5], 1); staged[sl] = (unsigned)s4.y | ((unsigned)d4.y << 16);
            sl = atomicAdd(&hist[d4.z >> 5], 1); staged[sl] = (unsigned)s4.z | ((unsigned)d4.z << 16);
            sl = atomicAdd(&hist[d4.w >> 5], 1); staged[sl] = (unsigned)s4.w | ((unsigned)d4.w << 16);
        } else {
            for (int j = k; j < nE; ++j) {
                int s0 = ed[base + j];
                int d0 = ed[E + base + j];
                int sl = atomicAdd(&hist[d0 >> 5], 1);
                staged[sl] = (unsigned)s0 | ((unsigned)d0 << 16);
            }
        }
    }
    __syncthreads();
    unsigned* bo = bdata + (size_t)c * E;
    for (int sI = t; sI < nE; sI += 256) {
        unsigned rec = staged[sI];
        int b = (int)(rec >> 16) >> 5;
        bo[off[b] + sI] = rec;
    }
}

// ---- within-bucket 32-way counting sort, SG buckets per block ----
__global__ void __launch_bounds__(256) k_sort32(const unsigned* __restrict__ bdata,
        const int* __restrict__ bstart, int* __restrict__ sdat,
        int* __restrict__ rs, float* __restrict__ dinv, int E, int N, int NB) {
    int c = blockIdx.y;
    int b0 = blockIdx.x * SG;
    __shared__ int cnt[SG * RPB];
    __shared__ int cur[SG * RPB];
    __shared__ int sb[SG + 1];
    int t = threadIdx.x;
    if (t < SG * RPB) cnt[t] = 0;
    if (t <= SG) {
        int b = b0 + t; if (b > NB) b = NB;
        sb[t] = bstart[c * (NB + 1) + b];
    }
    __syncthreads();
    int s0 = sb[0], sE = sb[SG];
    const unsigned* bd = bdata + (size_t)c * E;
    for (int i = s0 + t; i < sE; i += 256) {
        int dst = (int)(bd[i] >> 16);
        atomicAdd(&cnt[((dst >> 5) - b0) * RPB + (dst & 31)], 1);
    }
    __syncthreads();
    {
        int v = cnt[t];
        int s = v;
        #pragma unroll
        for (int off = 1; off < RPB; off <<= 1) {
            int u = __shfl_up(s, off, RPB);
            if ((t & (RPB - 1)) >= off) s += u;
        }
        int g = t >> 5, r = t & 31;
        int ex = sb[g] + s - v;
        cur[t] = ex;
        int row = (b0 + g) * RPB + r;
        if (b0 + g < NB && row < N) {
            rs[c * (N + 1) + row] = ex;
            dinv[c * N + row] = rsqrtf((float)(v + 1));
        }
    }
    if (blockIdx.x == 0 && t == 0) rs[c * (N + 1) + N] = E;
    __syncthreads();
    int* so = sdat + (size_t)c * E;
    for (int i = s0 + t; i < sE; i += 256) {
        unsigned r = bd[i];
        int dst = (int)(r >> 16);
        int slot = atomicAdd(&cur[((dst >> 5) - b0) * RPB + (dst & 31)], 1);
        so[slot] = (int)(r & 0xFFFFu);
    }
}

// ---- h planes: hl[c,row,0:32], hh[c,row,32:64] = fp16((x.W)*dinv) ----
__global__ void __launch_bounds__(256) k_gemm_all(const float* __restrict__ xs_,
        const float* __restrict__ xg_, const float* __restrict__ W0,
        const float* __restrict__ W1, const float* __restrict__ W2,
        const float* __restrict__ dinv, __half* __restrict__ hl,
        __half* __restrict__ hh, int N) {
    int c = blockIdx.y;
    const float* x = (c == 2) ? xg_ : xs_;
    const float* W = (c == 0) ? W0 : (c == 1) ? W1 : W2;
    __shared__ float Ws[CCH * CCH];       // [k][col]
    __shared__ float xT[CCH * (GR + 1)];  // [k][row], stride 65
    int t = threadIdx.x;
    int row0 = blockIdx.x * GR;
    #pragma unroll
    for (int j = 0; j < 4; ++j) {
        int idx = j * 1024 + t * 4;
        *(float4*)(Ws + idx) = *(const float4*)(W + idx);
    }
    #pragma unroll
    for (int j = 0; j < 4; ++j) {
        int idx = t + j * 256;
        int r = idx >> 4;
        int c0 = (idx & 15) * 4;
        int row = row0 + r;
        float4 v = make_float4(0.f, 0.f, 0.f, 0.f);
        if (row < N) v = *(const float4*)(x + (size_t)row * CCH + c0);
        xT[(c0 + 0) * (GR + 1) + r] = v.x;
        xT[(c0 + 1) * (GR + 1) + r] = v.y;
        xT[(c0 + 2) * (GR + 1) + r] = v.z;
        xT[(c0 + 3) * (GR + 1) + r] = v.w;
    }
    __syncthreads();
    int c4 = (t & 15) * 4;
    int r0 = (t >> 4) * 4;
    float4 a0 = make_float4(0.f, 0.f, 0.f, 0.f), a1 = a0, a2 = a0, a3 = a0;
    #pragma unroll 8
    for (int k = 0; k < CCH; ++k) {
        float4 wv = *(float4*)(Ws + k * CCH + c4);
        float x0 = xT[k * (GR + 1) + r0 + 0];
        float x1 = xT[k * (GR + 1) + r0 + 1];
        float x2 = xT[k * (GR + 1) + r0 + 2];
        float x3 = xT[k * (GR + 1) + r0 + 3];
        a0.x += x0 * wv.x; a0.y += x0 * wv.y; a0.z += x0 * wv.z; a0.w += x0 * wv.w;
        a1.x += x1 * wv.x; a1.y += x1 * wv.y; a1.z += x1 * wv.z; a1.w += x1 * wv.w;
        a2.x += x2 * wv.x; a2.y += x2 * wv.y; a2.z += x2 * wv.z; a2.w += x2 * wv.w;
        a3.x += x3 * wv.x; a3.y += x3 * wv.y; a3.z += x3 * wv.z; a3.w += x3 * wv.w;
    }
    const float* dv = dinv + c * N;
    __half* hp = (c4 < HCH) ? hl : hh;      // plane select (uniform per thread)
    int cp = (c4 < HCH) ? c4 : c4 - HCH;
    float4 av[4] = {a0, a1, a2, a3};
    #pragma unroll
    for (int i = 0; i < 4; ++i) {
        int row = row0 + r0 + i;
        if (row < N) {
            float dd = dv[row];
            union { __half2 h2[2]; float2 f2; } u;
            u.h2[0] = __floats2half2_rn(av[i].x * dd, av[i].y * dd);
            u.h2[1] = __floats2half2_rn(av[i].z * dd, av[i].w * dd);
            *(float2*)(hp + ((size_t)c * N + row) * HCH + cp) = u.f2;
        }
    }
}

// ---- gather 2 fp16 channels (4B) from a 64B-row plane ----
__device__ __forceinline__ float2 gat2(const __half* __restrict__ hc, int s, int l16) {
    __half2 h = ((const __half2*)(hc + (size_t)s * HCH))[l16];
    return __half22float2(h);
}

// ---- fused pull, XCD-split over PLANAR h: blocks with (j%8)<4 handle the
//      low plane, others the high plane. Each XCD's gathers touch only its
//      own 64B-row plane (3.2MB/conv -> L2-resident). ----
__global__ void __launch_bounds__(256) k_pull(const int* __restrict__ rs,
        const int* __restrict__ sdat, const __half* __restrict__ hl,
        const __half* __restrict__ hh, const float* __restrict__ dinv,
        const float* __restrict__ b0, const float* __restrict__ b1,
        const float* __restrict__ b2,
        float* __restrict__ out, int N, int E) {
    int j = blockIdx.x;
    int half = (j & 4) ? 1 : 0;
    int g = (j >> 3) * 4 + (j & 3);
    int row = g * 4 + (threadIdx.x >> 6);
    if (row >= 2 * N) return;
    int lane = threadIdx.x & 63;
    int q = lane >> 4;                      // quarter 0..3
    int l16 = lane & 15;
    size_t NH = (size_t)N * HCH;
    const __half* hp = half ? hh : hl;
    int choff = half * HCH;

    const __half* hcL;
    const int* sdL;
    int beg, end;
    float ddL;
    float2 bias;
    float* op;
    float2 acc = make_float2(0.f, 0.f);
    if (row < N) {                          // star: q0,q1=conv0; q2,q3=conv1
        int cv = q >> 1;
        const int* rsA = rs + cv * (N + 1);
        int bg = rsA[row], eg = rsA[row + 1];
        int mid = (bg + eg) >> 1;
        beg = (q & 1) ? mid : bg;
        end = (q & 1) ? eg : mid;
        hcL = hp + (size_t)cv * NH;
        sdL = sdat + (size_t)cv * E;
        ddL = dinv[cv * N + row];
        if (!(q & 1)) acc = gat2(hcL, row, l16);     // self-loop once per conv
        float2 bv0 = ((const float2*)(b0 + choff))[l16];
        float2 bv1 = ((const float2*)(b1 + choff))[l16];
        bias = make_float2(bv0.x + bv1.x, bv0.y + bv1.y);
        op = out + (size_t)row * CCH + choff;
    } else {                                // gal: 4 segments of one list
        int r = row - N;
        const int* rs2 = rs + 2 * (N + 1);
        int bg = rs2[r], eg = rs2[r + 1];
        int len = eg - bg;
        beg = bg + ((len * q) >> 2);
        end = bg + ((len * (q + 1)) >> 2);
        hcL = hp + 2 * NH;
        sdL = sdat + 2 * (size_t)E;
        ddL = dinv[2 * N + r];
        if (q == 0) acc = gat2(hcL, r, l16);
        bias = ((const float2*)(b2 + choff))[l16];
        op = out + (size_t)N * CCH + (size_t)r * CCH + choff;
    }

    int i = beg;
    for (; i + 7 < end; i += 8) {           // 8 edges per quarter in flight
        int4a q0 = *(const int4a*)(sdL + i);
        int4a q1 = *(const int4a*)(sdL + i + 4);
        float2 v0 = gat2(hcL, q0.x, l16);
        float2 v1 = gat2(hcL, q0.y, l16);
        float2 v2 = gat2(hcL, q0.z, l16);
        float2 v3 = gat2(hcL, q0.w, l16);
        float2 v4 = gat2(hcL, q1.x, l16);
        float2 v5 = gat2(hcL, q1.y, l16);
        float2 v6 = gat2(hcL, q1.z, l16);
        float2 v7 = gat2(hcL, q1.w, l16);
        acc.x += ((v0.x + v1.x) + (v2.x + v3.x)) + ((v4.x + v5.x) + (v6.x + v7.x));
        acc.y += ((v0.y + v1.y) + (v2.y + v3.y)) + ((v4.y + v5.y) + (v6.y + v7.y));
    }
    for (; i + 3 < end; i += 4) {
        int4a q0 = *(const int4a*)(sdL + i);
        float2 v0 = gat2(hcL, q0.x, l16);
        float2 v1 = gat2(hcL, q0.y, l16);
        float2 v2 = gat2(hcL, q0.z, l16);
        float2 v3 = gat2(hcL, q0.w, l16);
        acc.x += (v0.x + v1.x) + (v2.x + v3.x);
        acc.y += (v0.y + v1.y) + (v2.y + v3.y);
    }
    for (; i < end; ++i) {
        float2 v = gat2(hcL, sdL[i], l16);
        acc.x += v.x; acc.y += v.y;
    }

    float2 t;
    t.x = acc.x * ddL; t.y = acc.y * ddL;
    t.x += __shfl_xor(t.x, 16, 64); t.y += __shfl_xor(t.y, 16, 64);
    t.x += __shfl_xor(t.x, 32, 64); t.y += __shfl_xor(t.y, 32, 64);
    if (lane < 16) {
        t.x += bias.x; t.y += bias.y;
        ((float2*)op)[l16] = t;
    }
}

static inline size_t align256(size_t x) { return (x + 255) & ~(size_t)255; }

extern "C" void kernel_launch(void* const* d_in, const int* in_sizes, int n_in,
                              void* d_out, int out_size, void* d_ws, size_t ws_size,
                              hipStream_t stream) {
    const float* x_star = (const float*)d_in[0];
    const float* x_gal  = (const float*)d_in[1];
    const int*   e_ssn  = (const int*)d_in[2];
    const int*   e_ssf  = (const int*)d_in[3];
    const int*   e_ggn  = (const int*)d_in[4];
    const float* W_ssn  = (const float*)d_in[5];
    const float* W_ssf  = (const float*)d_in[6];
    const float* W_ggn  = (const float*)d_in[7];
    const float* b_ssn  = (const float*)d_in[8];
    const float* b_ssf  = (const float*)d_in[9];
    const float* b_ggn  = (const float*)d_in[10];

    const int N  = in_sizes[0] / CCH;       // 50000 (src+dst fit 16-bit pack)
    const int E  = in_sizes[2] / 2;         // 1000000
    const size_t NH = (size_t)N * HCH;
    const int NB   = (N + RPB - 1) / RPB;   // 1563 buckets per conv
    const int NBLK = (E + PCH - 1) / PCH;   // 123 partition blocks per conv

    // workspace layout
    char* w = (char*)d_ws;
    __half*   hl     = (__half*)w;   w += align256((size_t)3 * NH * 2);
    __half*   hh     = (__half*)w;   w += align256((size_t)3 * NH * 2);
    float*    dinv   = (float*)w;    w += align256((size_t)3 * N * 4);
    unsigned* bdata  = (unsigned*)w; w += align256((size_t)3 * E * 4);
    int*      sdat   = (int*)w;      w += align256((size_t)3 * E * 4);
    int*      H      = (int*)w;      w += align256((size_t)3 * NBLK * NB * 4);
    int*      bstart = (int*)w;      w += align256((size_t)3 * (NB + 1) * 4);
    int*      rs     = (int*)w;      w += align256((size_t)3 * (N + 1) * 4);

    const int B = 256;

    k_hist<<<dim3(NBLK, 3), B, 0, stream>>>(e_ssn, e_ssf, e_ggn, H, E, NB, NBLK);
    k_bscan<<<3, 1024, 0, stream>>>(H, bstart, NB, NBLK, E);
    k_colscan<<<dim3((NB + 3) / 4, 3), B, 0, stream>>>(H, bstart, NB, NBLK);
    k_part2<<<dim3(NBLK, 3), B, 0, stream>>>(e_ssn, e_ssf, e_ggn, H, bdata, E, NB, NBLK);
    k_sort32<<<dim3((NB + SG - 1) / SG, 3), B, 0, stream>>>(bdata, bstart, sdat,
                                                            rs, dinv, E, N, NB);
    k_gemm_all<<<dim3((N + GR - 1) / GR, 3), B, 0, stream>>>(x_star, x_gal,
                                                             W_ssn, W_ssf, W_ggn,
                                                             dinv, hl, hh, N);
    // 2x blocks: row-group g = (j>>3)*4 + (j&3), plane = (j>>2)&1.
    int G = (2 * N + 3) / 4;                // row-groups (25000, %4==0)
    k_pull<<<2 * G, B, 0, stream>>>(rs, sdat, hl, hh, dinv,
                                    b_ssn, b_ssf, b_ggn,
                                    (float*)d_out, N, E);
}

// Round 16
// 243.303 us; speedup vs baseline: 1.3021x; 1.3021x over previous
//
#include <hip/hip_runtime.h>
#include <hip/hip_fp16.h>

#define CCH 64      // channels
#define RPB 32      // rows per bucket
#define PCH 8192    // edges per partition block
#define NBMAX 1568  // >= NB = ceil(50000/32) = 1563
#define GR 64       // rows per gemm block
#define SG 8        // buckets per sort block
#define STCAP 8192  // sort32 LDS staging capacity (recs)

typedef int int4a __attribute__((ext_vector_type(4), aligned(4)));

// ---- pass A: per-block bucket histogram -> H[c][blk][b]; also cnt totals ----
__global__ void __launch_bounds__(256) k_hist(const int* __restrict__ e0,
        const int* __restrict__ e1, const int* __restrict__ e2,
        int* __restrict__ H, int* __restrict__ cnt, int E, int NB, int NBLK) {
    int c = blockIdx.y;
    const int* dd = ((c == 0) ? e0 : (c == 1) ? e1 : e2) + E;
    int base = blockIdx.x * PCH;
    int nE = E - base; if (nE > PCH) nE = PCH;
    __shared__ int hist[NBMAX];
    int t = threadIdx.x;
    for (int i = t; i < NB; i += 256) hist[i] = 0;
    __syncthreads();
    for (int k = t * 4; k < nE; k += 1024) {
        if (k + 3 < nE) {
            int4a d = *(const int4a*)(dd + base + k);
            atomicAdd(&hist[d.x >> 5], 1); atomicAdd(&hist[d.y >> 5], 1);
            atomicAdd(&hist[d.z >> 5], 1); atomicAdd(&hist[d.w >> 5], 1);
        } else {
            for (int j = k; j < nE; ++j) atomicAdd(&hist[dd[base + j] >> 5], 1);
        }
    }
    __syncthreads();
    int* Hrow = H + ((size_t)c * NBLK + blockIdx.x) * NB;
    for (int i = t; i < NB; i += 256) {
        int h = hist[i];
        Hrow[i] = h;
        if (h) atomicAdd(&cnt[c * NB + i], h);
    }
}

// ---- exclusive scan of NB bucket totals per conv -> bstart ----
__global__ void __launch_bounds__(1024) k_bscan(const int* __restrict__ cnt,
        int* __restrict__ bstart, int NB, int E) {
    int c = blockIdx.x, t = threadIdx.x;
    __shared__ int sm[1024];
    int i0 = 2 * t, i1 = 2 * t + 1;
    int v0 = (i0 < NB) ? cnt[c * NB + i0] : 0;
    int v1 = (i1 < NB) ? cnt[c * NB + i1] : 0;
    sm[t] = v0 + v1;
    __syncthreads();
    #pragma unroll
    for (int off = 1; off < 1024; off <<= 1) {
        int u = (t >= off) ? sm[t - off] : 0;
        __syncthreads();
        sm[t] += u;
        __syncthreads();
    }
    int ex = sm[t] - (v0 + v1);
    if (i0 < NB) bstart[c * (NB + 1) + i0] = ex;
    if (i1 < NB) bstart[c * (NB + 1) + i1] = ex + v0;
    if (t == 0) bstart[c * (NB + 1) + NB] = E;
}

// ---- pass B: per-bucket scan over blocks: H <- bstart + prefix ----
__global__ void __launch_bounds__(256) k_colscan(int* __restrict__ H,
        const int* __restrict__ bstart, int NB, int NBLK) {
    int c = blockIdx.y;
    int b = blockIdx.x * 4 + (threadIdx.x >> 6);
    if (b >= NB) return;
    int l = threadIdx.x & 63;
    int* Hc = H + (size_t)c * NBLK * NB;
    int run = bstart[c * (NB + 1) + b];
    for (int c0 = 0; c0 < NBLK; c0 += 64) {
        int blk = c0 + l;
        int v = (blk < NBLK) ? Hc[(size_t)blk * NB + b] : 0;
        int s = v;
        #pragma unroll
        for (int off = 1; off < 64; off <<= 1) {
            int u = __shfl_up(s, off, 64);
            if (l >= off) s += u;
        }
        if (blk < NBLK) Hc[(size_t)blk * NB + b] = run + s - v;
        run += __shfl(s, 63, 64);
    }
}

// ---- pass C: LDS-STAGED partition (bucket-ordered staging, linear copy-out) ----
__global__ void __launch_bounds__(256) k_part2(const int* __restrict__ e0,
        const int* __restrict__ e1, const int* __restrict__ e2,
        const int* __restrict__ H, unsigned* __restrict__ bdata,
        int E, int NB, int NBLK) {
    int c = blockIdx.y;
    const int* ed = (c == 0) ? e0 : (c == 1) ? e1 : e2;
    int base = blockIdx.x * PCH;
    int nE = E - base; if (nE > PCH) nE = PCH;
    __shared__ unsigned staged[PCH];    // 32 KB
    __shared__ int hist[NBMAX];
    __shared__ int off[NBMAX];
    __shared__ int sm[256];
    int t = threadIdx.x;
    for (int i = t; i < NB; i += 256) hist[i] = 0;
    const int* Hrow = H + ((size_t)c * NBLK + blockIdx.x) * NB;
    for (int i = t; i < NB; i += 256) off[i] = Hrow[i];
    __syncthreads();
    for (int k = t * 4; k < nE; k += 1024) {
        if (k + 3 < nE) {
            int4a d = *(const int4a*)(ed + E + base + k);
            atomicAdd(&hist[d.x >> 5], 1); atomicAdd(&hist[d.y >> 5], 1);
            atomicAdd(&hist[d.z >> 5], 1); atomicAdd(&hist[d.w >> 5], 1);
        } else {
            for (int j = k; j < nE; ++j) atomicAdd(&hist[ed[E + base + j] >> 5], 1);
        }
    }
    __syncthreads();
    int C = (NB + 255) >> 8;
    int lo = t * C, hi = lo + C; if (hi > NB) hi = NB; if (lo > NB) lo = NB;
    int s = 0;
    for (int i = lo; i < hi; ++i) s += hist[i];
    sm[t] = s;
    __syncthreads();
    #pragma unroll
    for (int o = 1; o < 256; o <<= 1) {
        int u = (t >= o) ? sm[t - o] : 0;
        __syncthreads();
        sm[t] += u;
        __syncthreads();
    }
    int run = (t == 0) ? 0 : sm[t - 1];
    for (int i = lo; i < hi; ++i) {
        int h = hist[i];
        off[i] -= run;
        hist[i] = run;
        run += h;
    }
    __syncthreads();
    for (int k = t * 4; k < nE; k += 1024) {
        if (k + 3 < nE) {
            int4a s4 = *(const int4a*)(ed + base + k);
            int4a d4 = *(const int4a*)(ed + E + base + k);
            int sl;
            sl = atomicAdd(&hist[d4.x >> 5], 1); staged[sl] = (unsigned)s4.x | ((unsigned)d4.x << 16);
            sl = atomicAdd(&hist[d4.y >> 5], 1); staged[sl] = (unsigned)s4.y | ((unsigned)d4.y << 16);
            sl = atomicAdd(&hist[d4.z >> 5], 1); staged[sl] = (unsigned)s4.z | ((unsigned)d4.z << 16);
            sl = atomicAdd(&hist[d4.w >> 5], 1); staged[sl] = (unsigned)s4.w | ((unsigned)d4.w << 16);
        } else {
            for (int j = k; j < nE; ++j) {
                int s0 = ed[base + j];
                int d0 = ed[E + base + j];
                int sl = atomicAdd(&hist[d0 >> 5], 1);
                staged[sl] = (unsigned)s0 | ((unsigned)d0 << 16);
            }
        }
    }
    __syncthreads();
    unsigned* bo = bdata + (size_t)c * E;
    for (int sI = t; sI < nE; sI += 256) {
        unsigned rec = staged[sI];
        int b = (int)(rec >> 16) >> 5;
        bo[off[b] + sI] = rec;
    }
}

// ---- within-bucket 32-way counting sort, SG buckets per block,
//      SINGLE global read: recs staged in LDS (fallback if region > STCAP) ----
__global__ void __launch_bounds__(256) k_sort32(const unsigned* __restrict__ bdata,
        const int* __restrict__ bstart, int* __restrict__ sdat,
        int* __restrict__ rs, float* __restrict__ dinv, int E, int N, int NB) {
    int c = blockIdx.y;
    int b0 = blockIdx.x * SG;
    __shared__ unsigned staged[STCAP];  // 32 KB
    __shared__ int cnt[SG * RPB];
    __shared__ int cur[SG * RPB];
    __shared__ int sb[SG + 1];
    int t = threadIdx.x;
    cnt[t] = 0;
    if (t <= SG) {
        int b = b0 + t; if (b > NB) b = NB;
        sb[t] = bstart[c * (NB + 1) + b];
    }
    __syncthreads();
    int s0 = sb[0], sE = sb[SG];
    int n = sE - s0;
    const unsigned* bd = bdata + (size_t)c * E;
    bool fits = (n <= STCAP);
    if (fits) {
        for (int i = t; i < n; i += 256) staged[i] = bd[s0 + i];
        __syncthreads();
        for (int i = t; i < n; i += 256) {
            int dst = (int)(staged[i] >> 16);
            atomicAdd(&cnt[((dst >> 5) - b0) * RPB + (dst & 31)], 1);
        }
    } else {
        for (int i = s0 + t; i < sE; i += 256) {
            int dst = (int)(bd[i] >> 16);
            atomicAdd(&cnt[((dst >> 5) - b0) * RPB + (dst & 31)], 1);
        }
    }
    __syncthreads();
    {
        int v = cnt[t];
        int s = v;
        #pragma unroll
        for (int off = 1; off < RPB; off <<= 1) {
            int u = __shfl_up(s, off, RPB);
            if ((t & (RPB - 1)) >= off) s += u;
        }
        int g = t >> 5, r = t & 31;
        int ex = sb[g] + s - v;
        cur[t] = ex;
        int row = (b0 + g) * RPB + r;
        if (b0 + g < NB && row < N) {
            rs[c * (N + 1) + row] = ex;
            dinv[c * N + row] = rsqrtf((float)(v + 1));
        }
    }
    if (blockIdx.x == 0 && t == 0) rs[c * (N + 1) + N] = E;
    __syncthreads();
    int* so = sdat + (size_t)c * E;
    if (fits) {
        for (int i = t; i < n; i += 256) {
            unsigned r = staged[i];
            int dst = (int)(r >> 16);
            int slot = atomicAdd(&cur[((dst >> 5) - b0) * RPB + (dst & 31)], 1);
            so[slot] = (int)(r & 0xFFFFu);
        }
    } else {
        for (int i = s0 + t; i < sE; i += 256) {
            unsigned r = bd[i];
            int dst = (int)(r >> 16);
            int slot = atomicAdd(&cur[((dst >> 5) - b0) * RPB + (dst & 31)], 1);
            so[slot] = (int)(r & 0xFFFFu);
        }
    }
}

// ---- h16[c,row,:] = fp16( (x_row . W_c) * dinv[c,row] ), register-tiled ----
__global__ void __launch_bounds__(256) k_gemm_all(const float* __restrict__ xs_,
        const float* __restrict__ xg_, const float* __restrict__ W0,
        const float* __restrict__ W1, const float* __restrict__ W2,
        const float* __restrict__ dinv, __half* __restrict__ h16, int N) {
    int c = blockIdx.y;
    const float* x = (c == 2) ? xg_ : xs_;
    const float* W = (c == 0) ? W0 : (c == 1) ? W1 : W2;
    __shared__ float Ws[CCH * CCH];       // [k][col]
    __shared__ float xT[CCH * (GR + 1)];  // [k][row], stride 65
    int t = threadIdx.x;
    int row0 = blockIdx.x * GR;
    #pragma unroll
    for (int j = 0; j < 4; ++j) {
        int idx = j * 1024 + t * 4;
        *(float4*)(Ws + idx) = *(const float4*)(W + idx);
    }
    #pragma unroll
    for (int j = 0; j < 4; ++j) {
        int idx = t + j * 256;
        int r = idx >> 4;
        int c0 = (idx & 15) * 4;
        int row = row0 + r;
        float4 v = make_float4(0.f, 0.f, 0.f, 0.f);
        if (row < N) v = *(const float4*)(x + (size_t)row * CCH + c0);
        xT[(c0 + 0) * (GR + 1) + r] = v.x;
        xT[(c0 + 1) * (GR + 1) + r] = v.y;
        xT[(c0 + 2) * (GR + 1) + r] = v.z;
        xT[(c0 + 3) * (GR + 1) + r] = v.w;
    }
    __syncthreads();
    int c4 = (t & 15) * 4;
    int r0 = (t >> 4) * 4;
    float4 a0 = make_float4(0.f, 0.f, 0.f, 0.f), a1 = a0, a2 = a0, a3 = a0;
    #pragma unroll 8
    for (int k = 0; k < CCH; ++k) {
        float4 wv = *(float4*)(Ws + k * CCH + c4);
        float x0 = xT[k * (GR + 1) + r0 + 0];
        float x1 = xT[k * (GR + 1) + r0 + 1];
        float x2 = xT[k * (GR + 1) + r0 + 2];
        float x3 = xT[k * (GR + 1) + r0 + 3];
        a0.x += x0 * wv.x; a0.y += x0 * wv.y; a0.z += x0 * wv.z; a0.w += x0 * wv.w;
        a1.x += x1 * wv.x; a1.y += x1 * wv.y; a1.z += x1 * wv.z; a1.w += x1 * wv.w;
        a2.x += x2 * wv.x; a2.y += x2 * wv.y; a2.z += x2 * wv.z; a2.w += x2 * wv.w;
        a3.x += x3 * wv.x; a3.y += x3 * wv.y; a3.z += x3 * wv.z; a3.w += x3 * wv.w;
    }
    const float* dv = dinv + c * N;
    __half* hc = h16 + (size_t)c * N * CCH;
    float4 av[4] = {a0, a1, a2, a3};
    #pragma unroll
    for (int i = 0; i < 4; ++i) {
        int row = row0 + r0 + i;
        if (row < N) {
            float dd = dv[row];
            union { __half2 h2[2]; float2 f2; } u;
            u.h2[0] = __floats2half2_rn(av[i].x * dd, av[i].y * dd);
            u.h2[1] = __floats2half2_rn(av[i].z * dd, av[i].w * dd);
            *(float2*)(hc + (size_t)row * CCH + c4) = u.f2;
        }
    }
}

// ---- gather 4 fp16 channels (8B dwordx2) ----
__device__ __forceinline__ float4 gat4(const __half* __restrict__ hc, int s, int l16) {
    union { float2 f2; __half2 h2[2]; } u;
    u.f2 = ((const float2*)(hc + (size_t)s * CCH))[l16];
    float2 a = __half22float2(u.h2[0]);
    float2 b = __half22float2(u.h2[1]);
    return make_float4(a.x, a.y, b.x, b.y);
}

__device__ __forceinline__ void acc4(float4& a, float4 v) {
    a.x += v.x; a.y += v.y; a.z += v.z; a.w += v.w;
}

// ---- fused pull: wave per row; four quarter-waves (16 lanes x 4ch) walk
//      4 list segments in lockstep (R13 winner). ----
__global__ void __launch_bounds__(256) k_pull(const int* __restrict__ rs,
        const int* __restrict__ sdat, const __half* __restrict__ h16,
        const float* __restrict__ dinv,
        const float* __restrict__ b0, const float* __restrict__ b1,
        const float* __restrict__ b2,
        float* __restrict__ out, int N, int E) {
    int row = blockIdx.x * 4 + (threadIdx.x >> 6);
    if (row >= 2 * N) return;
    int lane = threadIdx.x & 63;
    int q = lane >> 4;          // quarter 0..3
    int l16 = lane & 15;
    size_t NC = (size_t)N * CCH;

    const __half* hcL;
    const int* sdL;
    int beg, end;
    float ddL;
    float4 bias;
    float* op;
    float4 acc = make_float4(0.f, 0.f, 0.f, 0.f);
    if (row < N) {                          // star: q0,q1=conv0; q2,q3=conv1
        int cv = q >> 1;
        const int* rsA = rs + cv * (N + 1);
        int bg = rsA[row], eg = rsA[row + 1];
        int mid = (bg + eg) >> 1;
        beg = (q & 1) ? mid : bg;
        end = (q & 1) ? eg : mid;
        hcL = h16 + (size_t)cv * NC;
        sdL = sdat + (size_t)cv * E;
        ddL = dinv[cv * N + row];
        if (!(q & 1)) acc = gat4(hcL, row, l16);     // self-loop once per conv
        float4 bv0 = ((const float4*)b0)[l16];
        float4 bv1 = ((const float4*)b1)[l16];
        bias = make_float4(bv0.x + bv1.x, bv0.y + bv1.y,
                           bv0.z + bv1.z, bv0.w + bv1.w);
        op = out + (size_t)row * CCH;
    } else {                                // gal: 4 segments of one list
        int r = row - N;
        const int* rs2 = rs + 2 * (N + 1);
        int bg = rs2[r], eg = rs2[r + 1];
        int len = eg - bg;
        beg = bg + ((len * q) >> 2);
        end = bg + ((len * (q + 1)) >> 2);
        hcL = h16 + 2 * NC;
        sdL = sdat + 2 * (size_t)E;
        ddL = dinv[2 * N + r];
        if (q == 0) acc = gat4(hcL, r, l16);
        bias = ((const float4*)b2)[l16];
        op = out + NC + (size_t)r * CCH;
    }

    int i = beg;
    for (; i + 7 < end; i += 8) {           // 8 edges per quarter in flight
        int4a q0 = *(const int4a*)(sdL + i);
        int4a q1 = *(const int4a*)(sdL + i + 4);
        float4 v0 = gat4(hcL, q0.x, l16);
        float4 v1 = gat4(hcL, q0.y, l16);
        float4 v2 = gat4(hcL, q0.z, l16);
        float4 v3 = gat4(hcL, q0.w, l16);
        float4 v4 = gat4(hcL, q1.x, l16);
        float4 v5 = gat4(hcL, q1.y, l16);
        float4 v6 = gat4(hcL, q1.z, l16);
        float4 v7 = gat4(hcL, q1.w, l16);
        acc4(acc, v0); acc4(acc, v1); acc4(acc, v2); acc4(acc, v3);
        acc4(acc, v4); acc4(acc, v5); acc4(acc, v6); acc4(acc, v7);
    }
    for (; i + 3 < end; i += 4) {
        int4a q0 = *(const int4a*)(sdL + i);
        float4 v0 = gat4(hcL, q0.x, l16);
        float4 v1 = gat4(hcL, q0.y, l16);
        float4 v2 = gat4(hcL, q0.z, l16);
        float4 v3 = gat4(hcL, q0.w, l16);
        acc4(acc, v0); acc4(acc, v1); acc4(acc, v2); acc4(acc, v3);
    }
    for (; i < end; ++i) acc4(acc, gat4(hcL, sdL[i], l16));

    float4 t;
    t.x = acc.x * ddL; t.y = acc.y * ddL; t.z = acc.z * ddL; t.w = acc.w * ddL;
    t.x += __shfl_xor(t.x, 16, 64); t.y += __shfl_xor(t.y, 16, 64);
    t.z += __shfl_xor(t.z, 16, 64); t.w += __shfl_xor(t.w, 16, 64);
    t.x += __shfl_xor(t.x, 32, 64); t.y += __shfl_xor(t.y, 32, 64);
    t.z += __shfl_xor(t.z, 32, 64); t.w += __shfl_xor(t.w, 32, 64);
    if (lane < 16) {
        t.x += bias.x; t.y += bias.y; t.z += bias.z; t.w += bias.w;
        ((float4*)op)[l16] = t;
    }
}

static inline size_t align256(size_t x) { return (x + 255) & ~(size_t)255; }

extern "C" void kernel_launch(void* const* d_in, const int* in_sizes, int n_in,
                              void* d_out, int out_size, void* d_ws, size_t ws_size,
                              hipStream_t stream) {
    const float* x_star = (const float*)d_in[0];
    const float* x_gal  = (const float*)d_in[1];
    const int*   e_ssn  = (const int*)d_in[2];
    const int*   e_ssf  = (const int*)d_in[3];
    const int*   e_ggn  = (const int*)d_in[4];
    const float* W_ssn  = (const float*)d_in[5];
    const float* W_ssf  = (const float*)d_in[6];
    const float* W_ggn  = (const float*)d_in[7];
    const float* b_ssn  = (const float*)d_in[8];
    const float* b_ssf  = (const float*)d_in[9];
    const float* b_ggn  = (const float*)d_in[10];

    const int N  = in_sizes[0] / CCH;       // 50000 (src+dst fit 16-bit pack)
    const int E  = in_sizes[2] / 2;         // 1000000
    const size_t NC = (size_t)N * CCH;
    const int NB   = (N + RPB - 1) / RPB;   // 1563 buckets per conv
    const int NBLK = (E + PCH - 1) / PCH;   // 123 partition blocks per conv

    // workspace layout
    char* w = (char*)d_ws;
    __half*   h16    = (__half*)w;   w += align256((size_t)3 * NC * 2);
    float*    dinv   = (float*)w;    w += align256((size_t)3 * N * 4);
    unsigned* bdata  = (unsigned*)w; w += align256((size_t)3 * E * 4);
    int*      sdat   = (int*)w;      w += align256((size_t)3 * E * 4);
    int*      H      = (int*)w;      w += align256((size_t)3 * NBLK * NB * 4);
    int*      cnt    = (int*)w;      w += align256((size_t)3 * NB * 4);
    int*      bstart = (int*)w;      w += align256((size_t)3 * (NB + 1) * 4);
    int*      rs     = (int*)w;      w += align256((size_t)3 * (N + 1) * 4);

    const int B = 256;

    hipMemsetAsync(cnt, 0, (size_t)3 * NB * 4, stream);
    k_hist<<<dim3(NBLK, 3), B, 0, stream>>>(e_ssn, e_ssf, e_ggn, H, cnt, E, NB, NBLK);
    k_bscan<<<3, 1024, 0, stream>>>(cnt, bstart, NB, E);
    k_colscan<<<dim3((NB + 3) / 4, 3), B, 0, stream>>>(H, bstart, NB, NBLK);
    k_part2<<<dim3(NBLK, 3), B, 0, stream>>>(e_ssn, e_ssf, e_ggn, H, bdata, E, NB, NBLK);
    k_sort32<<<dim3((NB + SG - 1) / SG, 3), B, 0, stream>>>(bdata, bstart, sdat,
                                                            rs, dinv, E, N, NB);
    k_gemm_all<<<dim3((N + GR - 1) / GR, 3), B, 0, stream>>>(x_star, x_gal,
                                                             W_ssn, W_ssf, W_ggn,
                                                             dinv, h16, N);
    k_pull<<<(2 * N + 3) / 4, B, 0, stream>>>(rs, sdat, h16, dinv,
                                              b_ssn, b_ssf, b_ggn,
                                              (float*)d_out, N, E);
}